// Round 13
// baseline (812.777 us; speedup 1.0000x reference)
//
#include <hip/hip_runtime.h>
#include <stdint.h>

// Problem constants
#define TTOK 4096
#define DMODEL 512
#define NHEAD 8
#define FFDIM 2048
#define NLAYER 6

typedef short bf16x8 __attribute__((ext_vector_type(8)));
typedef float f32x4 __attribute__((ext_vector_type(4)));
typedef int v2i __attribute__((ext_vector_type(2)));

__device__ __forceinline__ unsigned short f2bf(float f) {
  union { float f; unsigned int u; } v; v.f = f;
  unsigned int u = v.u;
  unsigned int r = (u + 0x7FFFu + ((u >> 16) & 1u)) >> 16;
  return (unsigned short)r;
}

__device__ __forceinline__ float bf2f(unsigned short h) {
  union { unsigned int u; float f; } v; v.u = ((unsigned int)h) << 16;
  return v.f;
}

// global -> LDS direct (16B per lane). LDS dest must be wave-uniform base;
// lane writes base + lane*16. Source is per-lane.
#define GLOAD_LDS16(gp, lp)                                                      \
  __builtin_amdgcn_global_load_lds(                                              \
      (const __attribute__((address_space(1))) unsigned int*)(gp),               \
      (__attribute__((address_space(3))) unsigned int*)(lp), 16, 0, 0)

// ---------------------------------------------------------------------------
// Weight prep: transpose + cast f32 [K][N] -> bf16 [N][K]
// ---------------------------------------------------------------------------
__global__ void transpose_cast(const float* __restrict__ src, unsigned short* __restrict__ dst,
                               int K, int N) {
  __shared__ float tile[32][33];
  const int n0 = blockIdx.x * 32, k0 = blockIdx.y * 32;
  const int x = threadIdx.x, y = threadIdx.y;
#pragma unroll
  for (int yy = 0; yy < 32; yy += 8)
    tile[y + yy][x] = src[(size_t)(k0 + y + yy) * N + n0 + x];
  __syncthreads();
#pragma unroll
  for (int yy = 0; yy < 32; yy += 8)
    dst[(size_t)(n0 + yy + y) * K + k0 + x] = f2bf(tile[x][y + yy]);
}

__global__ void pack_bias(const float* __restrict__ bq, const float* __restrict__ bk,
                          const float* __restrict__ bv, const float* __restrict__ bc,
                          float* __restrict__ out) {
  int i = blockIdx.x * 256 + threadIdx.x;
  const float* src = (i < 512) ? bq : (i < 1024) ? bk : (i < 1536) ? bv : bc;
  out[i] = src[i & 511];
}

__global__ void cast_bf16(const float* __restrict__ src, unsigned short* __restrict__ dst, int n4) {
  int i = blockIdx.x * 256 + threadIdx.x;
  if (i < n4) {
    float4 v = ((const float4*)src)[i];
    uint2 o;
    o.x = (unsigned int)f2bf(v.x) | ((unsigned int)f2bf(v.y) << 16);
    o.y = (unsigned int)f2bf(v.z) | ((unsigned int)f2bf(v.w) << 16);
    ((uint2*)dst)[i] = o;
  }
}

__global__ void seg_bounds(const int* __restrict__ seg, int* __restrict__ ss,
                           int* __restrict__ se, int T) {
  const int t = blockIdx.x * 256 + threadIdx.x;
  if (t >= T) return;
  const int sid = seg[t];
  int lo = 0, hi = T;
  while (lo < hi) { int mid = (lo + hi) >> 1; if (seg[mid] < sid) lo = mid + 1; else hi = mid; }
  ss[t] = lo;
  lo = t; hi = T;
  while (lo < hi) { int mid = (lo + hi) >> 1; if (seg[mid] <= sid) lo = mid + 1; else hi = mid; }
  se[t] = lo;
}

// ---------------------------------------------------------------------------
// bf16 MFMA GEMM: C[M,N] = A[M,K] * Bt[N,K]^T  (+bias, optional res/swish)
// MODE 0: out_bf16 = acc + bias
// MODE 1: out_f32  = res + acc + bias
// MODE 2: out_bf16 = swish(acc + bias)
// MF = m-frags/wave; WM = waves along M (WN = 4/WM). BM = MF*16*WM, BN = 64*WN.
// 2-phase double-buffered LDS.
// ---------------------------------------------------------------------------
template <int MODE, int MF, int WM>
__launch_bounds__(256)
__global__ void gemm_bf16(const unsigned short* __restrict__ A,
                          const unsigned short* __restrict__ Bt,
                          int M, int N, int K,
                          const float* __restrict__ bias,
                          const float* __restrict__ res,
                          float* __restrict__ outF,
                          unsigned short* __restrict__ outB) {
  constexpr int WN = 4 / WM;
  constexpr int BM = MF * 16 * WM;
  constexpr int BN = 64 * WN;
  __shared__ uint4 As[2][BM * 8];  // per buf: BM rows x 8 x 16B
  __shared__ uint4 Bs[2][BN * 8];
  const int tid = threadIdx.x;
  const int lane = tid & 63;
  const int wv = tid >> 6;
  const int wm = wv / WN, wn = wv % WN;
  const int l15 = lane & 15, l4 = lane >> 4;
  const int bm0 = blockIdx.x * BM;
  const int bn0 = blockIdx.y * BN;

  f32x4 acc[MF][4];
#pragma unroll
  for (int m = 0; m < MF; ++m)
#pragma unroll
    for (int n = 0; n < 4; ++n) acc[m][n] = (f32x4){0.f, 0.f, 0.f, 0.f};

  auto stage = [&](int b, int k0) {
#pragma unroll
    for (int i = 0; i < (BM * 8) / 256; ++i) {
      const int u = tid + i * 256;
      const int r = u >> 3;
      const int c = (u & 7) ^ (r & 7);
      GLOAD_LDS16(A + (size_t)(bm0 + r) * K + k0 + c * 8, &As[b][i * 256 + wv * 64]);
    }
#pragma unroll
    for (int i = 0; i < (BN * 8) / 256; ++i) {
      const int u = tid + i * 256;
      const int r = u >> 3;
      const int c = (u & 7) ^ (r & 7);
      GLOAD_LDS16(Bt + (size_t)(bn0 + r) * K + k0 + c * 8, &Bs[b][i * 256 + wv * 64]);
    }
  };

  const int nt = K >> 6;
  stage(0, 0);
  __syncthreads();
  int bufi = 0;
  for (int t = 0; t < nt; ++t) {
    if (t + 1 < nt) stage(bufi ^ 1, (t + 1) << 6);
#pragma unroll
    for (int kk = 0; kk < 2; ++kk) {
      bf16x8 af[MF], bfr[4];
#pragma unroll
      for (int m = 0; m < MF; ++m) {
        const int row = wm * (MF * 16) + m * 16 + l15;
        const int c = kk * 4 + l4;
        af[m] = *(const bf16x8*)&As[bufi][row * 8 + (c ^ (row & 7))];
      }
#pragma unroll
      for (int n = 0; n < 4; ++n) {
        const int row = wn * 64 + n * 16 + l15;
        const int c = kk * 4 + l4;
        bfr[n] = *(const bf16x8*)&Bs[bufi][row * 8 + (c ^ (row & 7))];
      }
#pragma unroll
      for (int m = 0; m < MF; ++m)
#pragma unroll
        for (int n = 0; n < 4; ++n)
          acc[m][n] = __builtin_amdgcn_mfma_f32_16x16x32_bf16(af[m], bfr[n], acc[m][n], 0, 0, 0);
    }
    __syncthreads();
    bufi ^= 1;
  }

  float bvals[4];
#pragma unroll
  for (int n = 0; n < 4; ++n) bvals[n] = bias[bn0 + wn * 64 + n * 16 + l15];

#pragma unroll
  for (int m = 0; m < MF; ++m) {
#pragma unroll
    for (int r = 0; r < 4; ++r) {
      const int R = bm0 + wm * (MF * 16) + m * 16 + l4 * 4 + r;
#pragma unroll
      for (int n = 0; n < 4; ++n) {
        const int C = bn0 + wn * 64 + n * 16 + l15;
        float v = acc[m][n][r] + bvals[n];
        if (MODE == 1) {
          v += res[(size_t)R * N + C];
          outF[(size_t)R * N + C] = v;
        } else if (MODE == 2) {
          v = v / (1.f + __expf(-v));
          outB[(size_t)R * N + C] = f2bf(v);
        } else {
          outB[(size_t)R * N + C] = f2bf(v);
        }
      }
    }
  }
}

// ---------------------------------------------------------------------------
// Fused GEMM (N=512, full row per block) + bias + residual + TF LayerNorm.
// out = gamma*(x-u)/sqrt(var+eps)+beta, x = res + A@Bt + bias.
// Grid 256 blocks x 512 thr (8 waves); wave wn owns cols wn*64..+63 (4 frags,
// MF=1, BM=16 rows). A/B frags read directly from global (L2-resident).
// Cross-wave row stats via LDS. Writes f32 (residual/out) + bf16 (next GEMM).
// ---------------------------------------------------------------------------
__launch_bounds__(512)
__global__ void gemm_ln(const unsigned short* __restrict__ A,
                        const unsigned short* __restrict__ Bt,
                        int K,
                        const float* __restrict__ bias,
                        const float* __restrict__ res,
                        const float* __restrict__ gamma,
                        const float* __restrict__ beta,
                        float* __restrict__ outF,
                        unsigned short* __restrict__ outB) {
  __shared__ float red[8][16][2];
  const int tid = threadIdx.x;
  const int lane = tid & 63;
  const int wn = tid >> 6;  // 0..7
  const int l15 = lane & 15, l4 = lane >> 4;
  const int bm0 = blockIdx.x * 16;

  f32x4 acc[4];
#pragma unroll
  for (int n = 0; n < 4; ++n) acc[n] = (f32x4){0.f, 0.f, 0.f, 0.f};

  for (int k0 = 0; k0 < K; k0 += 32) {
    const bf16x8 af = *(const bf16x8*)(A + (size_t)(bm0 + l15) * K + k0 + l4 * 8);
#pragma unroll
    for (int n = 0; n < 4; ++n) {
      const int col = wn * 64 + n * 16 + l15;
      const bf16x8 bfr = *(const bf16x8*)(Bt + (size_t)col * K + k0 + l4 * 8);
      acc[n] = __builtin_amdgcn_mfma_f32_16x16x32_bf16(af, bfr, acc[n], 0, 0, 0);
    }
  }

  const int row_l = l4 * 4;
  float vals[4][4];
  float bsum[4] = {0.f, 0.f, 0.f, 0.f}, bsq[4] = {0.f, 0.f, 0.f, 0.f};
#pragma unroll
  for (int n = 0; n < 4; ++n) {
    const int col = wn * 64 + n * 16 + l15;
    const float bn = bias[col];
#pragma unroll
    for (int r = 0; r < 4; ++r) {
      const float v = acc[n][r] + bn + res[(size_t)(bm0 + row_l + r) * 512 + col];
      vals[n][r] = v;
      bsum[r] += v;
      bsq[r] += v * v;
    }
  }
#pragma unroll
  for (int off = 1; off < 16; off <<= 1) {
#pragma unroll
    for (int r = 0; r < 4; ++r) {
      bsum[r] += __shfl_xor(bsum[r], off);
      bsq[r] += __shfl_xor(bsq[r], off);
    }
  }
  if (l15 == 0) {
#pragma unroll
    for (int r = 0; r < 4; ++r) {
      red[wn][row_l + r][0] = bsum[r];
      red[wn][row_l + r][1] = bsq[r];
    }
  }
  __syncthreads();
  float mean[4], rstd[4];
#pragma unroll
  for (int r = 0; r < 4; ++r) {
    float S = 0.f, Q = 0.f;
#pragma unroll
    for (int w = 0; w < 8; ++w) {
      S += red[w][row_l + r][0];
      Q += red[w][row_l + r][1];
    }
    const float mu = S * (1.f / 512.f);
    mean[r] = mu;
    rstd[r] = rsqrtf(Q * (1.f / 512.f) - mu * mu + 1e-12f);
  }
#pragma unroll
  for (int n = 0; n < 4; ++n) {
    const int col = wn * 64 + n * 16 + l15;
    const float gm = gamma[col], bt = beta[col];
#pragma unroll
    for (int r = 0; r < 4; ++r) {
      const float y = (vals[n][r] - mean[r]) * rstd[r] * gm + bt;
      const size_t idx = (size_t)(bm0 + row_l + r) * 512 + col;
      outF[idx] = y;
      outB[idx] = f2bf(y);
    }
  }
}

// ---------------------------------------------------------------------------
// Segment-local flash attention, MFMA, ONE WAVE PER BLOCK (zero barriers).
// Flat grid 2048: head = bid&7 (one head per XCD -> L2-resident K/V),
// q0 = (bid>>3)*16. Single V buffer; STAGEV(next) issued after the tr-reads'
// lgkmcnt(0) fence; PV B-frags via ds_read_b64_tr_b16 on chunked LDS.
// Softmax denominator l computed on the MATRIX pipe: l += P @ ones via two
// extra MFMAs with a constant all-ones B-frag (every C column = row-sum),
// replacing the 4-round shuffle psum reduce.
// ---------------------------------------------------------------------------
__launch_bounds__(64)
__global__ void attn_mfma(const unsigned short* __restrict__ qkvcb,
                          const int* __restrict__ sstart,
                          const int* __restrict__ send,
                          unsigned short* __restrict__ aob) {
  __shared__ unsigned short Vt[4096];     // [4][64][16] bf16 = 8KB
  __shared__ unsigned short Pl[16 * 68];  // [row][key]
  const int lane = threadIdx.x;
  const int l15 = lane & 15;
  const int g = lane >> 4;
  const int head = blockIdx.x & 7;
  const int q0 = (blockIdx.x >> 3) * 16;

  const size_t qbase = (size_t)(q0 + l15) * 2048 + head * 64;
  const bf16x8 qf0 = *(const bf16x8*)(qkvcb + qbase + g * 8);
  const bf16x8 qf1 = *(const bf16x8*)(qkvcb + qbase + 32 + g * 8);
  const bf16x8 ones = {(short)0x3F80, (short)0x3F80, (short)0x3F80, (short)0x3F80,
                       (short)0x3F80, (short)0x3F80, (short)0x3F80, (short)0x3F80};

  int sr[4], er[4];
#pragma unroll
  for (int r = 0; r < 4; ++r) {
    const int q = q0 + 4 * g + r;
    sr[r] = sstart[q];
    er[r] = send[q];
  }
  const int s0 = sstart[q0];
  const int e1 = send[q0 + 15];

  const int vtokrel = lane >> 1;
  const unsigned short* vsrc = qkvcb + 1024 + head * 64 + (lane & 1) * 8;

  bf16x8 kfa[4], kfb[4];
  auto LOADK = [&](int k0) {
#pragma unroll
    for (int n = 0; n < 4; ++n) {
      const size_t kb =
          (size_t)min(k0 + 16 * n + l15, TTOK - 1) * 2048 + 512 + head * 64;
      kfa[n] = *(const bf16x8*)(qkvcb + kb + g * 8);
      kfb[n] = *(const bf16x8*)(qkvcb + kb + 32 + g * 8);
    }
  };
  auto STAGEV = [&](int k0) {
#pragma unroll
    for (int i = 0; i < 8; ++i) {
      const int tok = min(k0 + vtokrel + (i & 1) * 32, TTOK - 1);
      GLOAD_LDS16(vsrc + (size_t)tok * 2048 + (i >> 1) * 16, Vt + i * 512);
    }
  };

  STAGEV(s0);
  LOADK(s0);

  float m_[4], l_[4];
  f32x4 o[4];
#pragma unroll
  for (int r = 0; r < 4; ++r) { m_[r] = -1e30f; l_[r] = 0.f; }
#pragma unroll
  for (int n = 0; n < 4; ++n) o[n] = (f32x4){0.f, 0.f, 0.f, 0.f};

  for (int k0 = s0; k0 < e1; k0 += 64) {
    // ---- (a) S = Q K^T (vmcnt wait here drains V gloads too) ----
    f32x4 sac[4];
#pragma unroll
    for (int n = 0; n < 4; ++n) {
      f32x4 z = (f32x4){0.f, 0.f, 0.f, 0.f};
      z = __builtin_amdgcn_mfma_f32_16x16x32_bf16(qf0, kfa[n], z, 0, 0, 0);
      sac[n] = __builtin_amdgcn_mfma_f32_16x16x32_bf16(qf1, kfb[n], z, 0, 0, 0);
    }

    // ---- (b) scale + segment mask + online softmax (defer-max) ----
    float pv[4][4];  // [n][reg]
    float pmax[4] = {-1e30f, -1e30f, -1e30f, -1e30f};
#pragma unroll
    for (int n = 0; n < 4; ++n) {
      const int col = k0 + 16 * n + l15;
#pragma unroll
      for (int r = 0; r < 4; ++r) {
        float v = sac[n][r] * 0.125f;
        if (col < sr[r] || col >= er[r]) v = -1e30f;
        pv[n][r] = v;
        pmax[r] = fmaxf(pmax[r], v);
      }
    }
    bool need = false;
#pragma unroll
    for (int r = 0; r < 4; ++r) need |= (pmax[r] > m_[r] + 8.f);
    if (__any(need)) {
      float tm[4];
#pragma unroll
      for (int r = 0; r < 4; ++r) tm[r] = pmax[r];
#pragma unroll
      for (int off = 1; off < 16; off <<= 1) {
#pragma unroll
        for (int r = 0; r < 4; ++r) tm[r] = fmaxf(tm[r], __shfl_xor(tm[r], off));
      }
      f32x4 corrv;
#pragma unroll
      for (int r = 0; r < 4; ++r) {
        const float nm = fmaxf(m_[r], tm[r]);
        const float corr = __expf(m_[r] - nm);
        m_[r] = nm;
        l_[r] *= corr;
        corrv[r] = corr;
      }
#pragma unroll
      for (int n = 0; n < 4; ++n) o[n] *= corrv;
    }
#pragma unroll
    for (int n = 0; n < 4; ++n)
#pragma unroll
      for (int r = 0; r < 4; ++r) pv[n][r] = __expf(pv[n][r] - m_[r]);

    // ---- (c) P -> LDS, read A-frags, tr-read V, fence ----
#pragma unroll
    for (int n = 0; n < 4; ++n)
#pragma unroll
      for (int r = 0; r < 4; ++r)
        Pl[(4 * g + r) * 68 + 16 * n + l15] = f2bf(pv[n][r]);
    const bf16x8 pa0 = *(const bf16x8*)(Pl + l15 * 68 + g * 8);
    const bf16x8 pa1 = *(const bf16x8*)(Pl + l15 * 68 + 32 + g * 8);

    v2i t[16];
    {
      const __attribute__((address_space(3))) unsigned short* vb3 =
          ((const __attribute__((address_space(3))) unsigned short*)Vt) +
          g * 128 + l15 * 4;
      asm volatile("ds_read_b64_tr_b16 %0, %1"              : "=v"(t[0])  : "v"(vb3));
      asm volatile("ds_read_b64_tr_b16 %0, %1 offset:128"   : "=v"(t[1])  : "v"(vb3));
      asm volatile("ds_read_b64_tr_b16 %0, %1 offset:1024"  : "=v"(t[2])  : "v"(vb3));
      asm volatile("ds_read_b64_tr_b16 %0, %1 offset:1152"  : "=v"(t[3])  : "v"(vb3));
      asm volatile("ds_read_b64_tr_b16 %0, %1 offset:2048"  : "=v"(t[4])  : "v"(vb3));
      asm volatile("ds_read_b64_tr_b16 %0, %1 offset:2176"  : "=v"(t[5])  : "v"(vb3));
      asm volatile("ds_read_b64_tr_b16 %0, %1 offset:3072"  : "=v"(t[6])  : "v"(vb3));
      asm volatile("ds_read_b64_tr_b16 %0, %1 offset:3200"  : "=v"(t[7])  : "v"(vb3));
      asm volatile("ds_read_b64_tr_b16 %0, %1 offset:4096"  : "=v"(t[8])  : "v"(vb3));
      asm volatile("ds_read_b64_tr_b16 %0, %1 offset:4224"  : "=v"(t[9])  : "v"(vb3));
      asm volatile("ds_read_b64_tr_b16 %0, %1 offset:5120"  : "=v"(t[10]) : "v"(vb3));
      asm volatile("ds_read_b64_tr_b16 %0, %1 offset:5248"  : "=v"(t[11]) : "v"(vb3));
      asm volatile("ds_read_b64_tr_b16 %0, %1 offset:6144"  : "=v"(t[12]) : "v"(vb3));
      asm volatile("ds_read_b64_tr_b16 %0, %1 offset:6272"  : "=v"(t[13]) : "v"(vb3));
      asm volatile("ds_read_b64_tr_b16 %0, %1 offset:7168"  : "=v"(t[14]) : "v"(vb3));
      asm volatile("ds_read_b64_tr_b16 %0, %1 offset:7296"  : "=v"(t[15]) : "v"(vb3));
      asm volatile("s_waitcnt lgkmcnt(0)" ::: "memory");
      __builtin_amdgcn_sched_barrier(0);
    }

    // ---- (d) V reads done: issue next tile's staging + K loads ----
    const int k0n = (k0 + 64 < e1) ? (k0 + 64) : s0;
    STAGEV(k0n);
    LOADK(k0n);

    // ---- (e) PV MFMAs + l via P@ones (registers only) ----
    union VU { v2i p[2]; bf16x8 f; };
#pragma unroll
    for (int n = 0; n < 4; ++n) {
      VU u0, u1;
      u0.p[0] = t[4 * n];     u0.p[1] = t[4 * n + 1];
      u1.p[0] = t[4 * n + 2]; u1.p[1] = t[4 * n + 3];
      o[n] = __builtin_amdgcn_mfma_f32_16x16x32_bf16(pa0, u0.f, o[n], 0, 0, 0);
      o[n] = __builtin_amdgcn_mfma_f32_16x16x32_bf16(pa1, u1.f, o[n], 0, 0, 0);
    }
    {
      f32x4 lacc = (f32x4){0.f, 0.f, 0.f, 0.f};
      lacc = __builtin_amdgcn_mfma_f32_16x16x32_bf16(pa0, ones, lacc, 0, 0, 0);
      lacc = __builtin_amdgcn_mfma_f32_16x16x32_bf16(pa1, ones, lacc, 0, 0, 0);
#pragma unroll
      for (int r = 0; r < 4; ++r) l_[r] += lacc[r];
    }
  }

  // ---- normalize, add c, store ----
  float rl[4];
#pragma unroll
  for (int r = 0; r < 4; ++r) rl[r] = 1.f / l_[r];
#pragma unroll
  for (int n = 0; n < 4; ++n) {
#pragma unroll
    for (int r = 0; r < 4; ++r) {
      const int q = q0 + 4 * g + r;
      const int d = head * 64 + 16 * n + l15;
      const float cv = bf2f(qkvcb[(size_t)q * 2048 + 1536 + d]);
      aob[(size_t)q * 512 + d] = f2bf(o[n][r] * rl[r] + cv);
    }
  }
}

// ---------------------------------------------------------------------------
// TF-style LayerNorm over D=512 (used after FFN2 only)
// ---------------------------------------------------------------------------
__launch_bounds__(64)
__global__ void ln_kernel(const float* __restrict__ x, const float* __restrict__ g,
                          const float* __restrict__ b, float* __restrict__ outF,
                          unsigned short* __restrict__ outB) {
  const int row = blockIdx.x;
  const int lane = threadIdx.x;
  const float4* xr = (const float4*)(x + (size_t)row * 512);
  float4 a = xr[lane * 2], c = xr[lane * 2 + 1];
  float s = a.x + a.y + a.z + a.w + c.x + c.y + c.z + c.w;
  float sq = a.x * a.x + a.y * a.y + a.z * a.z + a.w * a.w +
             c.x * c.x + c.y * c.y + c.z * c.z + c.w * c.w;
#pragma unroll
  for (int off = 1; off < 64; off <<= 1) {
    s += __shfl_xor(s, off);
    sq += __shfl_xor(sq, off);
  }
  const float mean = s * (1.f / 512.f);
  const float var = sq * (1.f / 512.f) - mean * mean;
  const float rstd = rsqrtf(var + 1e-12f);
  const float4* gr = (const float4*)g;
  const float4* br = (const float4*)b;
  float4 g0 = gr[lane * 2], g1v = gr[lane * 2 + 1];
  float4 b0 = br[lane * 2], b1v = br[lane * 2 + 1];
  float4 y0, y1;
  y0.x = (a.x - mean) * rstd * g0.x + b0.x;
  y0.y = (a.y - mean) * rstd * g0.y + b0.y;
  y0.z = (a.z - mean) * rstd * g0.z + b0.z;
  y0.w = (a.w - mean) * rstd * g0.w + b0.w;
  y1.x = (c.x - mean) * rstd * g1v.x + b1v.x;
  y1.y = (c.y - mean) * rstd * g1v.y + b1v.y;
  y1.z = (c.z - mean) * rstd * g1v.z + b1v.z;
  y1.w = (c.w - mean) * rstd * g1v.w + b1v.w;
  float4* of = (float4*)(outF + (size_t)row * 512);
  of[lane * 2] = y0;
  of[lane * 2 + 1] = y1;
  uint4 ob;
  ob.x = (unsigned int)f2bf(y0.x) | ((unsigned int)f2bf(y0.y) << 16);
  ob.y = (unsigned int)f2bf(y0.z) | ((unsigned int)f2bf(y0.w) << 16);
  ob.z = (unsigned int)f2bf(y1.x) | ((unsigned int)f2bf(y1.y) << 16);
  ob.w = (unsigned int)f2bf(y1.z) | ((unsigned int)f2bf(y1.w) << 16);
  ((uint4*)(outB + (size_t)row * 512))[lane] = ob;
}

// ---------------------------------------------------------------------------
extern "C" void kernel_launch(void* const* d_in, const int* in_sizes, int n_in,
                              void* d_out, int out_size, void* d_ws, size_t ws_size,
                              hipStream_t stream) {
  const float* h_in = (const float*)d_in[0];
  const int* seg = (const int*)d_in[1];
  const float* Wq = (const float*)d_in[2];
  const float* bq = (const float*)d_in[3];
  const float* Wk = (const float*)d_in[4];
  const float* bk = (const float*)d_in[5];
  const float* Wv = (const float*)d_in[6];
  const float* bv = (const float*)d_in[7];
  const float* Wc = (const float*)d_in[8];
  const float* bc = (const float*)d_in[9];
  const float* Wp = (const float*)d_in[10];
  const float* bp = (const float*)d_in[11];
  const float* g1 = (const float*)d_in[12];
  const float* b1 = (const float*)d_in[13];
  const float* g2 = (const float*)d_in[14];
  const float* b2 = (const float*)d_in[15];
  const float* W1 = (const float*)d_in[16];
  const float* fb1 = (const float*)d_in[17];
  const float* W2 = (const float*)d_in[18];
  const float* fb2 = (const float*)d_in[19];
  float* outp = (float*)d_out;

  char* p = (char*)d_ws;
  auto alloc = [&](size_t bytes) {
    char* r = p;
    p += (bytes + 255) & ~(size_t)255;
    return r;
  };
  unsigned short* wqkvcb = (unsigned short*)alloc((size_t)2048 * 512 * 2);
  unsigned short* wpb = (unsigned short*)alloc((size_t)512 * 512 * 2);
  unsigned short* w1b = (unsigned short*)alloc((size_t)2048 * 512 * 2);
  unsigned short* w2b = (unsigned short*)alloc((size_t)512 * 2048 * 2);
  float* bqkvc = (float*)alloc(2048 * 4);
  unsigned short* hb = (unsigned short*)alloc((size_t)TTOK * 512 * 2);
  unsigned short* qkvcb = (unsigned short*)alloc((size_t)TTOK * 2048 * 2);
  unsigned short* aob = (unsigned short*)alloc((size_t)TTOK * 512 * 2);
  float* xbuf = (float*)alloc((size_t)TTOK * 512 * 4);
  float* h1 = (float*)alloc((size_t)TTOK * 512 * 4);
  unsigned short* h1b = (unsigned short*)alloc((size_t)TTOK * 512 * 2);
  unsigned short* f1b = (unsigned short*)alloc((size_t)TTOK * 2048 * 2);
  float* hcur = (float*)alloc((size_t)TTOK * 512 * 4);
  int* sstart = (int*)alloc(TTOK * 4);
  int* send = (int*)alloc(TTOK * 4);

  dim3 tb(32, 8);
  transpose_cast<<<dim3(16, 16), tb, 0, stream>>>(Wq, wqkvcb + 0 * 512 * 512, 512, 512);
  transpose_cast<<<dim3(16, 16), tb, 0, stream>>>(Wk, wqkvcb + 1 * 512 * 512, 512, 512);
  transpose_cast<<<dim3(16, 16), tb, 0, stream>>>(Wv, wqkvcb + 2 * 512 * 512, 512, 512);
  transpose_cast<<<dim3(16, 16), tb, 0, stream>>>(Wc, wqkvcb + 3 * 512 * 512, 512, 512);
  transpose_cast<<<dim3(16, 16), tb, 0, stream>>>(Wp, wpb, 512, 512);
  transpose_cast<<<dim3(64, 16), tb, 0, stream>>>(W1, w1b, 512, 2048);
  transpose_cast<<<dim3(16, 64), tb, 0, stream>>>(W2, w2b, 2048, 512);
  pack_bias<<<8, 256, 0, stream>>>(bq, bk, bv, bc, bqkvc);
  cast_bf16<<<2048, 256, 0, stream>>>(h_in, hb, TTOK * 512 / 4);
  seg_bounds<<<16, 256, 0, stream>>>(seg, sstart, send, TTOK);

  const float* resp = h_in;
  for (int layer = 0; layer < NLAYER; ++layer) {
    // QKVC projection: [4096,512] x [512,2048]
    gemm_bf16<0, 4, 2><<<dim3(32, 16), 256, 0, stream>>>(hb, wqkvcb, TTOK, 2048, 512,
                                                         bqkvc, nullptr, nullptr, qkvcb);
    // segment-local MFMA flash attention (+c), bf16 out
    attn_mfma<<<dim3(2048), 64, 0, stream>>>(qkvcb, sstart, send, aob);
    // fused: LN1(prev + aob@Wp + bp) -> h1 (f32) + h1b (bf16)
    gemm_ln<<<dim3(256), 512, 0, stream>>>(aob, wpb, 512, bp, resp, g1, b1, h1, h1b);
    // FFN1: swish(h1 @ W1 + fb1) -> f1b (bf16)
    gemm_bf16<2, 4, 2><<<dim3(32, 16), 256, 0, stream>>>(h1b, w1b, TTOK, 2048, 512,
                                                         fb1, nullptr, nullptr, f1b);
    // FFN2: f1 @ W2 + fb2 + h1 -> xbuf (f32); BM=64,BN=64 -> 512 blocks
    gemm_bf16<1, 1, 4><<<dim3(64, 8), 256, 0, stream>>>(f1b, w2b, TTOK, 512, 2048,
                                                        fb2, h1, xbuf, nullptr);
    float* lnout = (layer == NLAYER - 1) ? outp : hcur;
    ln_kernel<<<TTOK, 64, 0, stream>>>(xbuf, g2, b2, lnout, hb);
    resp = hcur;
  }
}

// Round 14
// 750.000 us; speedup vs baseline: 1.0837x; 1.0837x over previous
//
#include <hip/hip_runtime.h>
#include <stdint.h>

// Problem constants
#define TTOK 4096
#define DMODEL 512
#define NHEAD 8
#define FFDIM 2048
#define NLAYER 6

typedef short bf16x8 __attribute__((ext_vector_type(8)));
typedef float f32x4 __attribute__((ext_vector_type(4)));
typedef int v2i __attribute__((ext_vector_type(2)));

__device__ __forceinline__ unsigned short f2bf(float f) {
  union { float f; unsigned int u; } v; v.f = f;
  unsigned int u = v.u;
  unsigned int r = (u + 0x7FFFu + ((u >> 16) & 1u)) >> 16;
  return (unsigned short)r;
}

__device__ __forceinline__ float bf2f(unsigned short h) {
  union { unsigned int u; float f; } v; v.u = ((unsigned int)h) << 16;
  return v.f;
}

// global -> LDS direct (16B per lane). LDS dest must be wave-uniform base;
// lane writes base + lane*16. Source is per-lane.
#define GLOAD_LDS16(gp, lp)                                                      \
  __builtin_amdgcn_global_load_lds(                                              \
      (const __attribute__((address_space(1))) unsigned int*)(gp),               \
      (__attribute__((address_space(3))) unsigned int*)(lp), 16, 0, 0)

// ---------------------------------------------------------------------------
// Weight prep: transpose + cast f32 [K][N] -> bf16 [N][K]
// ---------------------------------------------------------------------------
__global__ void transpose_cast(const float* __restrict__ src, unsigned short* __restrict__ dst,
                               int K, int N) {
  __shared__ float tile[32][33];
  const int n0 = blockIdx.x * 32, k0 = blockIdx.y * 32;
  const int x = threadIdx.x, y = threadIdx.y;
#pragma unroll
  for (int yy = 0; yy < 32; yy += 8)
    tile[y + yy][x] = src[(size_t)(k0 + y + yy) * N + n0 + x];
  __syncthreads();
#pragma unroll
  for (int yy = 0; yy < 32; yy += 8)
    dst[(size_t)(n0 + yy + y) * K + k0 + x] = f2bf(tile[x][y + yy]);
}

__global__ void pack_bias(const float* __restrict__ bq, const float* __restrict__ bk,
                          const float* __restrict__ bv, const float* __restrict__ bc,
                          float* __restrict__ out) {
  int i = blockIdx.x * 256 + threadIdx.x;
  const float* src = (i < 512) ? bq : (i < 1024) ? bk : (i < 1536) ? bv : bc;
  out[i] = src[i & 511];
}

__global__ void cast_bf16(const float* __restrict__ src, unsigned short* __restrict__ dst, int n4) {
  int i = blockIdx.x * 256 + threadIdx.x;
  if (i < n4) {
    float4 v = ((const float4*)src)[i];
    uint2 o;
    o.x = (unsigned int)f2bf(v.x) | ((unsigned int)f2bf(v.y) << 16);
    o.y = (unsigned int)f2bf(v.z) | ((unsigned int)f2bf(v.w) << 16);
    ((uint2*)dst)[i] = o;
  }
}

__global__ void seg_bounds(const int* __restrict__ seg, int* __restrict__ ss,
                           int* __restrict__ se, int T) {
  const int t = blockIdx.x * 256 + threadIdx.x;
  if (t >= T) return;
  const int sid = seg[t];
  int lo = 0, hi = T;
  while (lo < hi) { int mid = (lo + hi) >> 1; if (seg[mid] < sid) lo = mid + 1; else hi = mid; }
  ss[t] = lo;
  lo = t; hi = T;
  while (lo < hi) { int mid = (lo + hi) >> 1; if (seg[mid] <= sid) lo = mid + 1; else hi = mid; }
  se[t] = lo;
}

// ---------------------------------------------------------------------------
// bf16 MFMA GEMM: C[M,N] = A[M,K] * Bt[N,K]^T  (+bias, optional res/swish)
// MODE 0: out_bf16 = acc + bias
// MODE 1: out_f32  = res + acc + bias
// MODE 2: out_bf16 = swish(acc + bias)
// MF = m-frags/wave; WM = waves along M (WN = 4/WM). BM = MF*16*WM, BN = 64*WN.
// 2-phase double-buffered LDS.
// ---------------------------------------------------------------------------
template <int MODE, int MF, int WM>
__launch_bounds__(256)
__global__ void gemm_bf16(const unsigned short* __restrict__ A,
                          const unsigned short* __restrict__ Bt,
                          int M, int N, int K,
                          const float* __restrict__ bias,
                          const float* __restrict__ res,
                          float* __restrict__ outF,
                          unsigned short* __restrict__ outB) {
  constexpr int WN = 4 / WM;
  constexpr int BM = MF * 16 * WM;
  constexpr int BN = 64 * WN;
  __shared__ uint4 As[2][BM * 8];  // per buf: BM rows x 8 x 16B
  __shared__ uint4 Bs[2][BN * 8];
  const int tid = threadIdx.x;
  const int lane = tid & 63;
  const int wv = tid >> 6;
  const int wm = wv / WN, wn = wv % WN;
  const int l15 = lane & 15, l4 = lane >> 4;
  const int bm0 = blockIdx.x * BM;
  const int bn0 = blockIdx.y * BN;

  f32x4 acc[MF][4];
#pragma unroll
  for (int m = 0; m < MF; ++m)
#pragma unroll
    for (int n = 0; n < 4; ++n) acc[m][n] = (f32x4){0.f, 0.f, 0.f, 0.f};

  auto stage = [&](int b, int k0) {
#pragma unroll
    for (int i = 0; i < (BM * 8) / 256; ++i) {
      const int u = tid + i * 256;
      const int r = u >> 3;
      const int c = (u & 7) ^ (r & 7);
      GLOAD_LDS16(A + (size_t)(bm0 + r) * K + k0 + c * 8, &As[b][i * 256 + wv * 64]);
    }
#pragma unroll
    for (int i = 0; i < (BN * 8) / 256; ++i) {
      const int u = tid + i * 256;
      const int r = u >> 3;
      const int c = (u & 7) ^ (r & 7);
      GLOAD_LDS16(Bt + (size_t)(bn0 + r) * K + k0 + c * 8, &Bs[b][i * 256 + wv * 64]);
    }
  };

  const int nt = K >> 6;
  stage(0, 0);
  __syncthreads();
  int bufi = 0;
  for (int t = 0; t < nt; ++t) {
    if (t + 1 < nt) stage(bufi ^ 1, (t + 1) << 6);
#pragma unroll
    for (int kk = 0; kk < 2; ++kk) {
      bf16x8 af[MF], bfr[4];
#pragma unroll
      for (int m = 0; m < MF; ++m) {
        const int row = wm * (MF * 16) + m * 16 + l15;
        const int c = kk * 4 + l4;
        af[m] = *(const bf16x8*)&As[bufi][row * 8 + (c ^ (row & 7))];
      }
#pragma unroll
      for (int n = 0; n < 4; ++n) {
        const int row = wn * 64 + n * 16 + l15;
        const int c = kk * 4 + l4;
        bfr[n] = *(const bf16x8*)&Bs[bufi][row * 8 + (c ^ (row & 7))];
      }
#pragma unroll
      for (int m = 0; m < MF; ++m)
#pragma unroll
        for (int n = 0; n < 4; ++n)
          acc[m][n] = __builtin_amdgcn_mfma_f32_16x16x32_bf16(af[m], bfr[n], acc[m][n], 0, 0, 0);
    }
    __syncthreads();
    bufi ^= 1;
  }

  float bvals[4];
#pragma unroll
  for (int n = 0; n < 4; ++n) bvals[n] = bias[bn0 + wn * 64 + n * 16 + l15];

#pragma unroll
  for (int m = 0; m < MF; ++m) {
#pragma unroll
    for (int r = 0; r < 4; ++r) {
      const int R = bm0 + wm * (MF * 16) + m * 16 + l4 * 4 + r;
#pragma unroll
      for (int n = 0; n < 4; ++n) {
        const int C = bn0 + wn * 64 + n * 16 + l15;
        float v = acc[m][n][r] + bvals[n];
        if (MODE == 1) {
          v += res[(size_t)R * N + C];
          outF[(size_t)R * N + C] = v;
        } else if (MODE == 2) {
          v = v / (1.f + __expf(-v));
          outB[(size_t)R * N + C] = f2bf(v);
        } else {
          outB[(size_t)R * N + C] = f2bf(v);
        }
      }
    }
  }
}

// ---------------------------------------------------------------------------
// Segment-local flash attention, MFMA, ONE WAVE PER BLOCK (zero barriers).
// Flat grid 2048: head = bid&7 (one head per XCD -> L2-resident K/V),
// q0 = (bid>>3)*16. KVBLK=128: two 64-key halves per iteration -> one
// lgkmcnt wait / one vmcnt drain / one defer-max / one P-roundtrip per 128
// keys, two independent QK->PV chains for ILP. V staged by global_load_lds
// into chunked [half][4][64][16] LDS; PV B-frags via ds_read_b64_tr_b16
// (16-lane group covers a 128B window linearly; HW delivers lane l15 <-
// column l15 of the 4x16 row-major window = V[tok0+j][dim l15]).
// l computed on the matrix pipe via P @ ones.
// ---------------------------------------------------------------------------
__launch_bounds__(64)
__global__ void attn_mfma(const unsigned short* __restrict__ qkvcb,
                          const int* __restrict__ sstart,
                          const int* __restrict__ send,
                          unsigned short* __restrict__ aob) {
  __shared__ unsigned short Vt[2][4096];   // [half][4][64][16] bf16 = 16KB
  __shared__ unsigned short Pl[16 * 136];  // [row][128 keys], stride 136
  const int lane = threadIdx.x;
  const int l15 = lane & 15;
  const int g = lane >> 4;
  const int head = blockIdx.x & 7;
  const int q0 = (blockIdx.x >> 3) * 16;

  const size_t qbase = (size_t)(q0 + l15) * 2048 + head * 64;
  const bf16x8 qf0 = *(const bf16x8*)(qkvcb + qbase + g * 8);
  const bf16x8 qf1 = *(const bf16x8*)(qkvcb + qbase + 32 + g * 8);
  const bf16x8 ones = {(short)0x3F80, (short)0x3F80, (short)0x3F80, (short)0x3F80,
                       (short)0x3F80, (short)0x3F80, (short)0x3F80, (short)0x3F80};

  int sr[4], er[4];
#pragma unroll
  for (int r = 0; r < 4; ++r) {
    const int q = q0 + 4 * g + r;
    sr[r] = sstart[q];
    er[r] = send[q];
  }
  const int s0 = sstart[q0];
  const int e1 = send[q0 + 15];

  const int vtokrel = lane >> 1;
  const unsigned short* vsrc = qkvcb + 1024 + head * 64 + (lane & 1) * 8;

  bf16x8 kfa[8], kfb[8];
  auto LOADK = [&](int k0) {
#pragma unroll
    for (int n = 0; n < 8; ++n) {
      const size_t kb =
          (size_t)min(k0 + 16 * n + l15, TTOK - 1) * 2048 + 512 + head * 64;
      kfa[n] = *(const bf16x8*)(qkvcb + kb + g * 8);
      kfb[n] = *(const bf16x8*)(qkvcb + kb + 32 + g * 8);
    }
  };
  auto STAGEV = [&](int k0, int h) {
#pragma unroll
    for (int i = 0; i < 8; ++i) {
      const int tok = min(k0 + vtokrel + (i & 1) * 32, TTOK - 1);
      GLOAD_LDS16(vsrc + (size_t)tok * 2048 + (i >> 1) * 16, &Vt[h][i * 512]);
    }
  };

  STAGEV(s0, 0);
  STAGEV(s0 + 64, 1);
  LOADK(s0);

  float m_[4], l_[4];
  f32x4 o[4];
#pragma unroll
  for (int r = 0; r < 4; ++r) { m_[r] = -1e30f; l_[r] = 0.f; }
#pragma unroll
  for (int n = 0; n < 4; ++n) o[n] = (f32x4){0.f, 0.f, 0.f, 0.f};

  for (int k0 = s0; k0 < e1; k0 += 128) {
    // ---- (a) S = Q K^T for both halves (vmcnt wait drains V gloads too) ----
    f32x4 sac[8];
#pragma unroll
    for (int n = 0; n < 8; ++n) {
      f32x4 z = (f32x4){0.f, 0.f, 0.f, 0.f};
      z = __builtin_amdgcn_mfma_f32_16x16x32_bf16(qf0, kfa[n], z, 0, 0, 0);
      sac[n] = __builtin_amdgcn_mfma_f32_16x16x32_bf16(qf1, kfb[n], z, 0, 0, 0);
    }

    // ---- (b) scale + segment mask + online softmax (defer-max, once) ----
    float pv[8][4];
    float pmax[4] = {-1e30f, -1e30f, -1e30f, -1e30f};
#pragma unroll
    for (int n = 0; n < 8; ++n) {
      const int col = k0 + 16 * n + l15;
#pragma unroll
      for (int r = 0; r < 4; ++r) {
        float v = sac[n][r] * 0.125f;
        if (col < sr[r] || col >= er[r]) v = -1e30f;
        pv[n][r] = v;
        pmax[r] = fmaxf(pmax[r], v);
      }
    }
    bool need = false;
#pragma unroll
    for (int r = 0; r < 4; ++r) need |= (pmax[r] > m_[r] + 8.f);
    if (__any(need)) {
      float tm[4];
#pragma unroll
      for (int r = 0; r < 4; ++r) tm[r] = pmax[r];
#pragma unroll
      for (int off = 1; off < 16; off <<= 1) {
#pragma unroll
        for (int r = 0; r < 4; ++r) tm[r] = fmaxf(tm[r], __shfl_xor(tm[r], off));
      }
      f32x4 corrv;
#pragma unroll
      for (int r = 0; r < 4; ++r) {
        const float nm = fmaxf(m_[r], tm[r]);
        const float corr = __expf(m_[r] - nm);
        m_[r] = nm;
        l_[r] *= corr;
        corrv[r] = corr;
      }
#pragma unroll
      for (int n = 0; n < 4; ++n) o[n] *= corrv;
    }
#pragma unroll
    for (int n = 0; n < 8; ++n)
#pragma unroll
      for (int r = 0; r < 4; ++r) pv[n][r] = __expf(pv[n][r] - m_[r]);

    // ---- (c) P -> LDS, read A-frags ----
#pragma unroll
    for (int n = 0; n < 8; ++n)
#pragma unroll
      for (int r = 0; r < 4; ++r)
        Pl[(4 * g + r) * 136 + 16 * n + l15] = f2bf(pv[n][r]);
    const bf16x8 pa0 = *(const bf16x8*)(Pl + l15 * 136 + g * 8);
    const bf16x8 pa1 = *(const bf16x8*)(Pl + l15 * 136 + 32 + g * 8);
    const bf16x8 pa2 = *(const bf16x8*)(Pl + l15 * 136 + 64 + g * 8);
    const bf16x8 pa3 = *(const bf16x8*)(Pl + l15 * 136 + 96 + g * 8);

    // ---- (d) tr-read both V halves, one fence ----
    v2i t0[16], t1[16];
    {
      const __attribute__((address_space(3))) unsigned short* vb3 =
          ((const __attribute__((address_space(3))) unsigned short*)&Vt[0][0]) +
          g * 128 + l15 * 4;
      asm volatile("ds_read_b64_tr_b16 %0, %1"               : "=v"(t0[0])  : "v"(vb3));
      asm volatile("ds_read_b64_tr_b16 %0, %1 offset:128"    : "=v"(t0[1])  : "v"(vb3));
      asm volatile("ds_read_b64_tr_b16 %0, %1 offset:1024"   : "=v"(t0[2])  : "v"(vb3));
      asm volatile("ds_read_b64_tr_b16 %0, %1 offset:1152"   : "=v"(t0[3])  : "v"(vb3));
      asm volatile("ds_read_b64_tr_b16 %0, %1 offset:2048"   : "=v"(t0[4])  : "v"(vb3));
      asm volatile("ds_read_b64_tr_b16 %0, %1 offset:2176"   : "=v"(t0[5])  : "v"(vb3));
      asm volatile("ds_read_b64_tr_b16 %0, %1 offset:3072"   : "=v"(t0[6])  : "v"(vb3));
      asm volatile("ds_read_b64_tr_b16 %0, %1 offset:3200"   : "=v"(t0[7])  : "v"(vb3));
      asm volatile("ds_read_b64_tr_b16 %0, %1 offset:4096"   : "=v"(t0[8])  : "v"(vb3));
      asm volatile("ds_read_b64_tr_b16 %0, %1 offset:4224"   : "=v"(t0[9])  : "v"(vb3));
      asm volatile("ds_read_b64_tr_b16 %0, %1 offset:5120"   : "=v"(t0[10]) : "v"(vb3));
      asm volatile("ds_read_b64_tr_b16 %0, %1 offset:5248"   : "=v"(t0[11]) : "v"(vb3));
      asm volatile("ds_read_b64_tr_b16 %0, %1 offset:6144"   : "=v"(t0[12]) : "v"(vb3));
      asm volatile("ds_read_b64_tr_b16 %0, %1 offset:6272"   : "=v"(t0[13]) : "v"(vb3));
      asm volatile("ds_read_b64_tr_b16 %0, %1 offset:7168"   : "=v"(t0[14]) : "v"(vb3));
      asm volatile("ds_read_b64_tr_b16 %0, %1 offset:7296"   : "=v"(t0[15]) : "v"(vb3));
      asm volatile("ds_read_b64_tr_b16 %0, %1 offset:8192"   : "=v"(t1[0])  : "v"(vb3));
      asm volatile("ds_read_b64_tr_b16 %0, %1 offset:8320"   : "=v"(t1[1])  : "v"(vb3));
      asm volatile("ds_read_b64_tr_b16 %0, %1 offset:9216"   : "=v"(t1[2])  : "v"(vb3));
      asm volatile("ds_read_b64_tr_b16 %0, %1 offset:9344"   : "=v"(t1[3])  : "v"(vb3));
      asm volatile("ds_read_b64_tr_b16 %0, %1 offset:10240"  : "=v"(t1[4])  : "v"(vb3));
      asm volatile("ds_read_b64_tr_b16 %0, %1 offset:10368"  : "=v"(t1[5])  : "v"(vb3));
      asm volatile("ds_read_b64_tr_b16 %0, %1 offset:11264"  : "=v"(t1[6])  : "v"(vb3));
      asm volatile("ds_read_b64_tr_b16 %0, %1 offset:11392"  : "=v"(t1[7])  : "v"(vb3));
      asm volatile("ds_read_b64_tr_b16 %0, %1 offset:12288"  : "=v"(t1[8])  : "v"(vb3));
      asm volatile("ds_read_b64_tr_b16 %0, %1 offset:12416"  : "=v"(t1[9])  : "v"(vb3));
      asm volatile("ds_read_b64_tr_b16 %0, %1 offset:13312"  : "=v"(t1[10]) : "v"(vb3));
      asm volatile("ds_read_b64_tr_b16 %0, %1 offset:13440"  : "=v"(t1[11]) : "v"(vb3));
      asm volatile("ds_read_b64_tr_b16 %0, %1 offset:14336"  : "=v"(t1[12]) : "v"(vb3));
      asm volatile("ds_read_b64_tr_b16 %0, %1 offset:14464"  : "=v"(t1[13]) : "v"(vb3));
      asm volatile("ds_read_b64_tr_b16 %0, %1 offset:15360"  : "=v"(t1[14]) : "v"(vb3));
      asm volatile("ds_read_b64_tr_b16 %0, %1 offset:15488"  : "=v"(t1[15]) : "v"(vb3));
      asm volatile("s_waitcnt lgkmcnt(0)" ::: "memory");
      __builtin_amdgcn_sched_barrier(0);
    }

    // ---- (e) V reads done: issue next iteration's staging + K loads ----
    const int k0n = (k0 + 128 < e1) ? (k0 + 128) : s0;
    STAGEV(k0n, 0);
    STAGEV(k0n + 64, 1);
    LOADK(k0n);

    // ---- (f) PV MFMAs (both halves) + l via P@ones ----
    union VU { v2i p[2]; bf16x8 f; };
#pragma unroll
    for (int n = 0; n < 4; ++n) {
      VU u0, u1, w0, w1;
      u0.p[0] = t0[4 * n];     u0.p[1] = t0[4 * n + 1];
      u1.p[0] = t0[4 * n + 2]; u1.p[1] = t0[4 * n + 3];
      w0.p[0] = t1[4 * n];     w0.p[1] = t1[4 * n + 1];
      w1.p[0] = t1[4 * n + 2]; w1.p[1] = t1[4 * n + 3];
      o[n] = __builtin_amdgcn_mfma_f32_16x16x32_bf16(pa0, u0.f, o[n], 0, 0, 0);
      o[n] = __builtin_amdgcn_mfma_f32_16x16x32_bf16(pa1, u1.f, o[n], 0, 0, 0);
      o[n] = __builtin_amdgcn_mfma_f32_16x16x32_bf16(pa2, w0.f, o[n], 0, 0, 0);
      o[n] = __builtin_amdgcn_mfma_f32_16x16x32_bf16(pa3, w1.f, o[n], 0, 0, 0);
    }
    {
      f32x4 lacc = (f32x4){0.f, 0.f, 0.f, 0.f};
      lacc = __builtin_amdgcn_mfma_f32_16x16x32_bf16(pa0, ones, lacc, 0, 0, 0);
      lacc = __builtin_amdgcn_mfma_f32_16x16x32_bf16(pa1, ones, lacc, 0, 0, 0);
      lacc = __builtin_amdgcn_mfma_f32_16x16x32_bf16(pa2, ones, lacc, 0, 0, 0);
      lacc = __builtin_amdgcn_mfma_f32_16x16x32_bf16(pa3, ones, lacc, 0, 0, 0);
#pragma unroll
      for (int r = 0; r < 4; ++r) l_[r] += lacc[r];
    }
  }

  // ---- normalize, add c, store ----
  float rl[4];
#pragma unroll
  for (int r = 0; r < 4; ++r) rl[r] = 1.f / l_[r];
#pragma unroll
  for (int n = 0; n < 4; ++n) {
#pragma unroll
    for (int r = 0; r < 4; ++r) {
      const int q = q0 + 4 * g + r;
      const int d = head * 64 + 16 * n + l15;
      const float cv = bf2f(qkvcb[(size_t)q * 2048 + 1536 + d]);
      aob[(size_t)q * 512 + d] = f2bf(o[n][r] * rl[r] + cv);
    }
  }
}

// ---------------------------------------------------------------------------
// TF-style LayerNorm over D=512: out = g*(x-u)/sqrt(var+1e-12)+b
// ---------------------------------------------------------------------------
__launch_bounds__(64)
__global__ void ln_kernel(const float* __restrict__ x, const float* __restrict__ g,
                          const float* __restrict__ b, float* __restrict__ outF,
                          unsigned short* __restrict__ outB) {
  const int row = blockIdx.x;
  const int lane = threadIdx.x;
  const float4* xr = (const float4*)(x + (size_t)row * 512);
  float4 a = xr[lane * 2], c = xr[lane * 2 + 1];
  float s = a.x + a.y + a.z + a.w + c.x + c.y + c.z + c.w;
  float sq = a.x * a.x + a.y * a.y + a.z * a.z + a.w * a.w +
             c.x * c.x + c.y * c.y + c.z * c.z + c.w * c.w;
#pragma unroll
  for (int off = 1; off < 64; off <<= 1) {
    s += __shfl_xor(s, off);
    sq += __shfl_xor(sq, off);
  }
  const float mean = s * (1.f / 512.f);
  const float var = sq * (1.f / 512.f) - mean * mean;
  const float rstd = rsqrtf(var + 1e-12f);
  const float4* gr = (const float4*)g;
  const float4* br = (const float4*)b;
  float4 g0 = gr[lane * 2], g1v = gr[lane * 2 + 1];
  float4 b0 = br[lane * 2], b1v = br[lane * 2 + 1];
  float4 y0, y1;
  y0.x = (a.x - mean) * rstd * g0.x + b0.x;
  y0.y = (a.y - mean) * rstd * g0.y + b0.y;
  y0.z = (a.z - mean) * rstd * g0.z + b0.z;
  y0.w = (a.w - mean) * rstd * g0.w + b0.w;
  y1.x = (c.x - mean) * rstd * g1v.x + b1v.x;
  y1.y = (c.y - mean) * rstd * g1v.y + b1v.y;
  y1.z = (c.z - mean) * rstd * g1v.z + b1v.z;
  y1.w = (c.w - mean) * rstd * g1v.w + b1v.w;
  float4* of = (float4*)(outF + (size_t)row * 512);
  of[lane * 2] = y0;
  of[lane * 2 + 1] = y1;
  uint4 ob;
  ob.x = (unsigned int)f2bf(y0.x) | ((unsigned int)f2bf(y0.y) << 16);
  ob.y = (unsigned int)f2bf(y0.z) | ((unsigned int)f2bf(y0.w) << 16);
  ob.z = (unsigned int)f2bf(y1.x) | ((unsigned int)f2bf(y1.y) << 16);
  ob.w = (unsigned int)f2bf(y1.z) | ((unsigned int)f2bf(y1.w) << 16);
  ((uint4*)(outB + (size_t)row * 512))[lane] = ob;
}

// ---------------------------------------------------------------------------
extern "C" void kernel_launch(void* const* d_in, const int* in_sizes, int n_in,
                              void* d_out, int out_size, void* d_ws, size_t ws_size,
                              hipStream_t stream) {
  const float* h_in = (const float*)d_in[0];
  const int* seg = (const int*)d_in[1];
  const float* Wq = (const float*)d_in[2];
  const float* bq = (const float*)d_in[3];
  const float* Wk = (const float*)d_in[4];
  const float* bk = (const float*)d_in[5];
  const float* Wv = (const float*)d_in[6];
  const float* bv = (const float*)d_in[7];
  const float* Wc = (const float*)d_in[8];
  const float* bc = (const float*)d_in[9];
  const float* Wp = (const float*)d_in[10];
  const float* bp = (const float*)d_in[11];
  const float* g1 = (const float*)d_in[12];
  const float* b1 = (const float*)d_in[13];
  const float* g2 = (const float*)d_in[14];
  const float* b2 = (const float*)d_in[15];
  const float* W1 = (const float*)d_in[16];
  const float* fb1 = (const float*)d_in[17];
  const float* W2 = (const float*)d_in[18];
  const float* fb2 = (const float*)d_in[19];
  float* outp = (float*)d_out;

  char* p = (char*)d_ws;
  auto alloc = [&](size_t bytes) {
    char* r = p;
    p += (bytes + 255) & ~(size_t)255;
    return r;
  };
  unsigned short* wqkvcb = (unsigned short*)alloc((size_t)2048 * 512 * 2);
  unsigned short* wpb = (unsigned short*)alloc((size_t)512 * 512 * 2);
  unsigned short* w1b = (unsigned short*)alloc((size_t)2048 * 512 * 2);
  unsigned short* w2b = (unsigned short*)alloc((size_t)512 * 2048 * 2);
  float* bqkvc = (float*)alloc(2048 * 4);
  unsigned short* hb = (unsigned short*)alloc((size_t)TTOK * 512 * 2);
  unsigned short* qkvcb = (unsigned short*)alloc((size_t)TTOK * 2048 * 2);
  unsigned short* aob = (unsigned short*)alloc((size_t)TTOK * 512 * 2);
  float* xbuf = (float*)alloc((size_t)TTOK * 512 * 4);
  float* h1 = (float*)alloc((size_t)TTOK * 512 * 4);
  unsigned short* h1b = (unsigned short*)alloc((size_t)TTOK * 512 * 2);
  unsigned short* f1b = (unsigned short*)alloc((size_t)TTOK * 2048 * 2);
  float* hcur = (float*)alloc((size_t)TTOK * 512 * 4);
  int* sstart = (int*)alloc(TTOK * 4);
  int* send = (int*)alloc(TTOK * 4);

  dim3 tb(32, 8);
  transpose_cast<<<dim3(16, 16), tb, 0, stream>>>(Wq, wqkvcb + 0 * 512 * 512, 512, 512);
  transpose_cast<<<dim3(16, 16), tb, 0, stream>>>(Wk, wqkvcb + 1 * 512 * 512, 512, 512);
  transpose_cast<<<dim3(16, 16), tb, 0, stream>>>(Wv, wqkvcb + 2 * 512 * 512, 512, 512);
  transpose_cast<<<dim3(16, 16), tb, 0, stream>>>(Wc, wqkvcb + 3 * 512 * 512, 512, 512);
  transpose_cast<<<dim3(16, 16), tb, 0, stream>>>(Wp, wpb, 512, 512);
  transpose_cast<<<dim3(64, 16), tb, 0, stream>>>(W1, w1b, 512, 2048);
  transpose_cast<<<dim3(16, 64), tb, 0, stream>>>(W2, w2b, 2048, 512);
  pack_bias<<<8, 256, 0, stream>>>(bq, bk, bv, bc, bqkvc);
  cast_bf16<<<2048, 256, 0, stream>>>(h_in, hb, TTOK * 512 / 4);
  seg_bounds<<<16, 256, 0, stream>>>(seg, sstart, send, TTOK);

  const float* resp = h_in;
  for (int layer = 0; layer < NLAYER; ++layer) {
    // QKVC projection: [4096,512] x [512,2048]
    gemm_bf16<0, 4, 2><<<dim3(32, 16), 256, 0, stream>>>(hb, wqkvcb, TTOK, 2048, 512,
                                                         bqkvc, nullptr, nullptr, qkvcb);
    // segment-local MFMA flash attention (+c), bf16 out
    attn_mfma<<<dim3(2048), 64, 0, stream>>>(qkvcb, sstart, send, aob);
    // attn_out @ Wp + bp + prev  -> xbuf (f32); BM=64,BN=64 -> 512 blocks
    gemm_bf16<1, 1, 4><<<dim3(64, 8), 256, 0, stream>>>(aob, wpb, TTOK, 512, 512,
                                                        bp, resp, xbuf, nullptr);
    ln_kernel<<<TTOK, 64, 0, stream>>>(xbuf, g1, b1, h1, h1b);
    // FFN1: swish(h1 @ W1 + fb1) -> f1b (bf16)
    gemm_bf16<2, 4, 2><<<dim3(32, 16), 256, 0, stream>>>(h1b, w1b, TTOK, 2048, 512,
                                                         fb1, nullptr, nullptr, f1b);
    // FFN2: f1 @ W2 + fb2 + h1 -> xbuf (f32); BM=64,BN=64 -> 512 blocks
    gemm_bf16<1, 1, 4><<<dim3(64, 8), 256, 0, stream>>>(f1b, w2b, TTOK, 512, 2048,
                                                        fb2, h1, xbuf, nullptr);
    float* lnout = (layer == NLAYER - 1) ? outp : hcur;
    ln_kernel<<<TTOK, 64, 0, stream>>>(xbuf, g2, b2, lnout, hb);
    resp = hcur;
  }
}